// Round 12
// baseline (149.676 us; speedup 1.0000x reference)
//
#include <hip/hip_runtime.h>
#include <hip/hip_bf16.h>

typedef __attribute__((ext_vector_type(4)))  float f32x4;
typedef __attribute__((ext_vector_type(16))) float f32x16;
typedef __attribute__((ext_vector_type(8)))  short bf16x8;
typedef __attribute__((ext_vector_type(4)))  unsigned u32x4;

#define S_LEN 4096
#define HEAD_D 64
#define WIN 256
#define QBLK 128
#define KVBLK 64
#define KSTR 72   // k_lds row stride (shorts)
#define VSTR 72   // vt_lds row stride (shorts), [d][key'] key' = key bits2<->3 swapped
#define QSCALE 0.18033688f   // log2(e)/8 folded into Q; no numerator shift

#define KBYTES (KVBLK * KSTR * 2)    // 9216 B per K buffer
#define VBYTES (HEAD_D * VSTR * 2)   // 9216 B per V buffer
#define KHALF  (KBYTES / 2)          // buffer stride in shorts (4608)
#define VHALF  (VBYTES / 2)
#define LPAR_OFF (2 * KBYTES + 2 * VBYTES)          // 36864
#define SMEM_BYTES (LPAR_OFF + 2 * 2 * 2 * 32 * 4)  // +1KB l partials = 37888

static __device__ __forceinline__ unsigned cvt2(float lo, float hi) {
  unsigned r;
  asm("v_cvt_pk_bf16_f32 %0, %1, %2" : "=v"(r) : "v"(lo), "v"(hi));
  return r;
}

// Publish barrier: drains LDS only; in-flight global prefetch loads ride across.
#define PUB_BARRIER() do {                              \
    __builtin_amdgcn_sched_barrier(0);                  \
    asm volatile("s_waitcnt lgkmcnt(0)" ::: "memory");  \
    __builtin_amdgcn_s_barrier();                       \
    __builtin_amdgcn_sched_barrier(0);                  \
  } while (0)

// 4 waves/block: wave = (qpair, kh). 64 q per wave (two 32-q sets sharing K/V frags)
// -> block-tile LDS reads halve vs 8-wave qg-split; 2x ILP per chain.
__global__ __launch_bounds__(256, 3)   // cap 170 VGPR (demand ~160); (256,4)=128 would spill
void swa_fwd(const float* __restrict__ Q, const float* __restrict__ K,
             const float* __restrict__ V, float* __restrict__ O) {
  __shared__ __attribute__((aligned(16))) char smem[SMEM_BYTES];

  const int tid   = threadIdx.x;
  const int widx  = tid >> 6;
  const int lane  = tid & 63;
  const int hi    = lane >> 5;
  const int c     = lane & 31;
  const int kh    = widx & 1;
  const int qpair = widx >> 1;
  const int kho   = kh * 32;

  // XCD swizzle: 4 contiguous bh per XCD, qb fastest.
  const int pb  = blockIdx.x;
  const int bh  = (pb & 7) * 4 + ((pb >> 3) >> 5);
  const int qb  = (pb >> 3) & 31;
  const int bq0 = qb * QBLK;
  const int q0  = bq0 + qpair * 64;   // this wave's 64 q rows

  const size_t base = (size_t)bh * S_LEN * HEAD_D;
  const float* Qp = Q + base;
  const float* Kp = K + base;
  const float* Vp = V + base;
  float*       Op = O + base;

  const f32x16 Z16 = {0.f,0.f,0.f,0.f,0.f,0.f,0.f,0.f,0.f,0.f,0.f,0.f,0.f,0.f,0.f,0.f};

  // ---- Q B-fragments for both 32-q sets ----
  bf16x8 aqA[4], aqB[4];
  #pragma unroll
  for (int set = 0; set < 2; ++set) {
    const float* qr = Qp + (size_t)(q0 + set * 32 + c) * HEAD_D + hi * 8;
    #pragma unroll
    for (int ch = 0; ch < 4; ++ch) {
      f32x4 x0 = *(const f32x4*)(qr + ch * 16);
      f32x4 x1 = *(const f32x4*)(qr + ch * 16 + 4);
      u32x4 au;
      au[0] = cvt2(x0[0] * QSCALE, x0[1] * QSCALE);
      au[1] = cvt2(x0[2] * QSCALE, x0[3] * QSCALE);
      au[2] = cvt2(x1[0] * QSCALE, x1[1] * QSCALE);
      au[3] = cvt2(x1[2] * QSCALE, x1[3] * QSCALE);
      if (set == 0) aqA[ch] = __builtin_bit_cast(bf16x8, au);
      else          aqB[ch] = __builtin_bit_cast(bf16x8, au);
    }
  }

  f32x16 accA0 = Z16, accA1 = Z16, accB0 = Z16, accB1 = Z16;
  float lsA0 = 0.f, lsA1 = 0.f, lsB0 = 0.f, lsB1 = 0.f;

  const int lo   = max(0, bq0 - WIN);
  const int khiB = min(S_LEN, bq0 + QBLK + WIN);
  const int nt   = (khiB - lo) >> 6;   // {6,8,10}: always even

  // staging assignment (256 threads): K 64x64 via 4 f32x4/thread; V via key-pair x 8 d
  const int krow  = tid >> 2;          // 0..63
  const int kc16  = (tid & 3) << 4;    // 0,16,32,48
  const int key2  = (tid & 31) << 1;   // 0..62 even
  const int key2p = (key2 & ~12) | ((key2 & 4) << 1) | ((key2 & 8) >> 1);  // bits 2<->3
  const int vd8   = (tid >> 5) << 3;   // 0..56

  // hoisted LDS bases
  short* const ksh = (short*)smem;
  short* const vsh = (short*)(smem + 2 * KBYTES);
  const short* const krd = ksh + (kho + c) * KSTR + hi * 8;
  const short* const vrd = vsh + c * VSTR + kho + hi * 8;
  short* const kwr = ksh + krow * KSTR + kc16;
  short* const vwr = vsh + vd8 * VSTR + key2p;

  unsigned koff = (unsigned)(lo + krow) * HEAD_D + kc16;
  unsigned voff = (unsigned)(lo + key2) * HEAD_D + vd8;

  f32x4 k0, k1, k2, k3;          // K staging (16 regs)
  f32x4 v00, v01, v10, v11;      // V staging (16 regs)
  #define LOAD_K() do {                         \
    k0 = *(const f32x4*)(Kp + koff);            \
    k1 = *(const f32x4*)(Kp + koff + 4);        \
    k2 = *(const f32x4*)(Kp + koff + 8);        \
    k3 = *(const f32x4*)(Kp + koff + 12);       \
    koff += KVBLK * HEAD_D;                     \
  } while (0)
  #define LOAD_V() do {                         \
    v00 = *(const f32x4*)(Vp + voff);           \
    v01 = *(const f32x4*)(Vp + voff + 4);       \
    v10 = *(const f32x4*)(Vp + voff + HEAD_D);  \
    v11 = *(const f32x4*)(Vp + voff + HEAD_D + 4); \
    voff += KVBLK * HEAD_D;                     \
  } while (0)
  #define STAGE_TO(BUF) do {                                        \
    u32x4 kw;                                                       \
    kw[0] = cvt2(k0[0], k0[1]);  kw[1] = cvt2(k0[2], k0[3]);        \
    kw[2] = cvt2(k1[0], k1[1]);  kw[3] = cvt2(k1[2], k1[3]);        \
    *(u32x4*)&kwr[(BUF) * KHALF] = kw;                              \
    kw[0] = cvt2(k2[0], k2[1]);  kw[1] = cvt2(k2[2], k2[3]);        \
    kw[2] = cvt2(k3[0], k3[1]);  kw[3] = cvt2(k3[2], k3[3]);        \
    *(u32x4*)&kwr[(BUF) * KHALF + 8] = kw;                          \
    _Pragma("unroll")                                               \
    for (int j = 0; j < 4; ++j)                                     \
      *(unsigned*)&vwr[(BUF) * VHALF + j * VSTR] = cvt2(v00[j], v10[j]); \
    _Pragma("unroll")                                               \
    for (int j = 0; j < 4; ++j)                                     \
      *(unsigned*)&vwr[(BUF) * VHALF + (4 + j) * VSTR] = cvt2(v01[j], v11[j]); \
  } while (0)

  #define TILE_BODY(T, BUF) do {                                                  \
    const int rel_ = lo + ((T) << 6) + kho - q0;                                  \
    f32x16 sA = Z16, sB = Z16;                                                    \
    __builtin_amdgcn_s_setprio(1);                                                \
    _Pragma("unroll")                                                             \
    for (int ch = 0; ch < 4; ++ch) {                                              \
      bf16x8 akf = *(const bf16x8*)&krd[(BUF) * KHALF + ch * 16];                 \
      sA = __builtin_amdgcn_mfma_f32_32x32x16_bf16(akf, aqA[ch], sA, 0, 0, 0);    \
      sB = __builtin_amdgcn_mfma_f32_32x32x16_bf16(akf, aqB[ch], sB, 0, 0, 0);    \
    }                                                                             \
    __builtin_amdgcn_s_setprio(0);                                                \
    if ((T) + 1 < nt) LOAD_K();                                                   \
    if (rel_ >= -192 && rel_ <= 224) {   /* band holds for all 64 q x 32 keys */  \
      _Pragma("unroll")                                                           \
      for (int g = 0; g < 16; g += 2) {                                           \
        const float a0 = __builtin_amdgcn_exp2f(sA[g]);                           \
        const float a1 = __builtin_amdgcn_exp2f(sA[g + 1]);                       \
        const float b0 = __builtin_amdgcn_exp2f(sB[g]);                           \
        const float b1 = __builtin_amdgcn_exp2f(sB[g + 1]);                       \
        sA[g] = a0; sA[g + 1] = a1; sB[g] = b0; sB[g + 1] = b1;                   \
        lsA0 += a0; lsA1 += a1; lsB0 += b0; lsB1 += b1;                           \
      }                                                                           \
    } else {                                                                      \
      const int bmA = rel_ + 4 * hi - c + WIN;                                    \
      _Pragma("unroll")                                                           \
      for (int g = 0; g < 16; ++g) {                                              \
        const int ro_ = (g & 3) + 8 * (g >> 2);                                   \
        const float a = ((unsigned)(bmA + ro_) <= 2u * WIN)                       \
                          ? __builtin_amdgcn_exp2f(sA[g]) : 0.f;                  \
        const float b = ((unsigned)(bmA - 32 + ro_) <= 2u * WIN)                  \
                          ? __builtin_amdgcn_exp2f(sB[g]) : 0.f;                  \
        sA[g] = a; sB[g] = b;                                                     \
        if (g & 1) { lsA1 += a; lsB1 += b; } else { lsA0 += a; lsB0 += b; }       \
      }                                                                           \
    }                                                                             \
    if ((T) + 1 < nt) LOAD_V();                                                   \
    __builtin_amdgcn_s_setprio(1);                                                \
    _Pragma("unroll")                                                             \
    for (int kt = 0; kt < 2; ++kt) {                                              \
      u32x4 pau;                                                                  \
      _Pragma("unroll")                                                           \
      for (int p2 = 0; p2 < 4; ++p2)                                              \
        pau[p2] = cvt2(sA[kt * 8 + 2 * p2], sA[kt * 8 + 2 * p2 + 1]);             \
      const bf16x8 paA = __builtin_bit_cast(bf16x8, pau);                         \
      _Pragma("unroll")                                                           \
      for (int p2 = 0; p2 < 4; ++p2)                                              \
        pau[p2] = cvt2(sB[kt * 8 + 2 * p2], sB[kt * 8 + 2 * p2 + 1]);             \
      const bf16x8 paB = __builtin_bit_cast(bf16x8, pau);                         \
      bf16x8 bv0 = *(const bf16x8*)&vrd[(BUF) * VHALF + kt * 16];                 \
      accA0 = __builtin_amdgcn_mfma_f32_32x32x16_bf16(paA, bv0, accA0, 0, 0, 0);  \
      accB0 = __builtin_amdgcn_mfma_f32_32x32x16_bf16(paB, bv0, accB0, 0, 0, 0);  \
      bf16x8 bv1 = *(const bf16x8*)&vrd[(BUF) * VHALF + kt * 16 + 32 * VSTR];     \
      accA1 = __builtin_amdgcn_mfma_f32_32x32x16_bf16(paA, bv1, accA1, 0, 0, 0);  \
      accB1 = __builtin_amdgcn_mfma_f32_32x32x16_bf16(paB, bv1, accB1, 0, 0, 0);  \
    }                                                                             \
    __builtin_amdgcn_s_setprio(0);                                                \
    if ((T) + 1 < nt) {                                                           \
      STAGE_TO((BUF) ^ 1);                                                        \
      PUB_BARRIER();                                                              \
    }                                                                             \
  } while (0)

  // prologue: stage tile 0 into buf 0 (one exposed vmcnt wait), then barrier
  LOAD_K();
  LOAD_V();
  STAGE_TO(0);
  PUB_BARRIER();

  for (int t = 0; t < nt; t += 2) {   // nt even: buffer index compile-time
    TILE_BODY(t, 0);
    TILE_BODY(t + 1, 1);
  }

  // ---- epilogue: merge kh halves per (qpair, set); overlay on dead K/V LDS ----
  float lsA = lsA0 + lsA1;  lsA += __shfl_xor(lsA, 32);
  float lsB = lsB0 + lsB1;  lsB += __shfl_xor(lsB, 32);
  __syncthreads();   // all tile reads done -> overlay safe
  float* o_mrg = (float*)smem;                   // [2 qpair][64 q][64 d] = 32 KB
  float* l_par = (float*)(smem + LPAR_OFF);      // [2 kh][2 qpair][2 set][32]
  if (hi == 0) {
    l_par[(((kh * 2 + qpair) * 2 + 0) * 32) + c] = lsA;
    l_par[(((kh * 2 + qpair) * 2 + 1) * 32) + c] = lsB;
  }
  if (kh == 0) {
    float* om = o_mrg + (size_t)qpair * 64 * HEAD_D;
    #pragma unroll
    for (int g = 0; g < 16; ++g) {
      const int qrow = (g & 3) + 8 * (g >> 2) + 4 * hi;
      om[qrow * HEAD_D + c]             = accA0[g];
      om[qrow * HEAD_D + 32 + c]        = accA1[g];
      om[(32 + qrow) * HEAD_D + c]      = accB0[g];
      om[(32 + qrow) * HEAD_D + 32 + c] = accB1[g];
    }
  }
  __syncthreads();
  if (kh == 1) {
    float* lp = l_par + qpair * 2 * 32;          // kh=0 slot, this qpair
    const float* lp1 = lp + 2 * 2 * 32 * 1;      // kh=1 slot offset: (1*2+qpair)*2*32 - qpair*2*32 = 128
    if (hi == 0) {
      lp[c]      = 1.0f / (lp[c]      + lp1[c]);       // set A inverse
      lp[32 + c] = 1.0f / (lp[32 + c] + lp1[32 + c]);  // set B inverse
    }
    __asm__ volatile("s_waitcnt lgkmcnt(0)" ::: "memory");
    __builtin_amdgcn_sched_barrier(0);
    const float* om = o_mrg + (size_t)qpair * 64 * HEAD_D;
    #pragma unroll
    for (int g = 0; g < 16; ++g) {
      const int qrow = (g & 3) + 8 * (g >> 2) + 4 * hi;
      const float ivA = lp[qrow];        // lane-uniform -> LDS broadcast
      const float ivB = lp[32 + qrow];
      float* orA = Op + (size_t)(q0 + qrow) * HEAD_D;
      float* orB = Op + (size_t)(q0 + 32 + qrow) * HEAD_D;
      orA[c]      = (om[qrow * HEAD_D + c]             + accA0[g]) * ivA;
      orA[32 + c] = (om[qrow * HEAD_D + 32 + c]        + accA1[g]) * ivA;
      orB[c]      = (om[(32 + qrow) * HEAD_D + c]      + accB0[g]) * ivB;
      orB[32 + c] = (om[(32 + qrow) * HEAD_D + 32 + c] + accB1[g]) * ivB;
    }
  }
}

extern "C" void kernel_launch(void* const* d_in, const int* in_sizes, int n_in,
                              void* d_out, int out_size, void* d_ws, size_t ws_size,
                              hipStream_t stream) {
  const float* q = (const float*)d_in[0];
  const float* k = (const float*)d_in[1];
  const float* v = (const float*)d_in[2];
  float* o = (float*)d_out;
  const int blocks = 2 * 16 * (S_LEN / QBLK);  // 1024
  swa_fwd<<<dim3(blocks), dim3(256), 0, stream>>>(q, k, v, o);
}

// Round 13
// 52.930 us; speedup vs baseline: 2.8278x; 2.8278x over previous
//
#include <hip/hip_runtime.h>
#include <hip/hip_bf16.h>

typedef __attribute__((ext_vector_type(4)))  float f32x4;
typedef __attribute__((ext_vector_type(16))) float f32x16;
typedef __attribute__((ext_vector_type(8)))  short bf16x8;
typedef __attribute__((ext_vector_type(4)))  unsigned u32x4;

#define S_LEN 4096
#define HEAD_D 64
#define WIN 256
#define QBLK 128
#define KVBLK 64
#define KSTR 72   // k_lds row stride (shorts)
#define VSTR 72   // vt_lds row stride (shorts), [d][key'] key' = key bits2<->3 swapped
#define QSCALE 0.18033688f   // log2(e)/8 folded into Q; no numerator shift

#define KBYTES (KVBLK * KSTR * 2)    // 9216 B per K buffer
#define VBYTES (HEAD_D * VSTR * 2)   // 9216 B per V buffer
#define KHALF  (KBYTES / 2)          // buffer stride in shorts (4608)
#define VHALF  (VBYTES / 2)
#define LPAR_OFF (2 * KBYTES + 2 * VBYTES)          // 36864
#define SMEM_BYTES (LPAR_OFF + 2 * 2 * 2 * 32 * 4)  // +1KB l partials = 37888

static __device__ __forceinline__ unsigned cvt2(float lo, float hi) {
  unsigned r;
  asm("v_cvt_pk_bf16_f32 %0, %1, %2" : "=v"(r) : "v"(lo), "v"(hi));
  return r;
}

// Publish barrier: drains LDS only; in-flight global prefetch loads ride across.
#define PUB_BARRIER() do {                              \
    __builtin_amdgcn_sched_barrier(0);                  \
    asm volatile("s_waitcnt lgkmcnt(0)" ::: "memory");  \
    __builtin_amdgcn_s_barrier();                       \
    __builtin_amdgcn_sched_barrier(0);                  \
  } while (0)

// 4 waves/block: wave = (qpair, kh), 64 q per wave (two 32-q sets share K/V frags)
// -> block-tile LDS reads halve vs 8-wave split; 2x ILP per chain.
// launch_bounds (256,2): VGPR cap 256 >> demand ~170. R12's (256,3) made the
// allocator pick 84 VGPR and spill 1.6GB; R7's (512,8) same disease. Never cap
// below demand.
__global__ __launch_bounds__(256, 2)
void swa_fwd(const float* __restrict__ Q, const float* __restrict__ K,
             const float* __restrict__ V, float* __restrict__ O) {
  __shared__ __attribute__((aligned(16))) char smem[SMEM_BYTES];

  const int tid   = threadIdx.x;
  const int widx  = tid >> 6;
  const int lane  = tid & 63;
  const int hi    = lane >> 5;
  const int c     = lane & 31;
  const int kh    = widx & 1;
  const int qpair = widx >> 1;
  const int kho   = kh * 32;

  // XCD swizzle: 4 contiguous bh per XCD, qb fastest.
  const int pb  = blockIdx.x;
  const int bh  = (pb & 7) * 4 + ((pb >> 3) >> 5);
  const int qb  = (pb >> 3) & 31;
  const int bq0 = qb * QBLK;
  const int q0  = bq0 + qpair * 64;   // this wave's 64 q rows

  const size_t base = (size_t)bh * S_LEN * HEAD_D;
  const float* Qp = Q + base;
  const float* Kp = K + base;
  const float* Vp = V + base;
  float*       Op = O + base;

  const f32x16 Z16 = {0.f,0.f,0.f,0.f,0.f,0.f,0.f,0.f,0.f,0.f,0.f,0.f,0.f,0.f,0.f,0.f};

  // ---- Q B-fragments for both 32-q sets ----
  bf16x8 aqA[4], aqB[4];
  #pragma unroll
  for (int set = 0; set < 2; ++set) {
    const float* qr = Qp + (size_t)(q0 + set * 32 + c) * HEAD_D + hi * 8;
    #pragma unroll
    for (int ch = 0; ch < 4; ++ch) {
      f32x4 x0 = *(const f32x4*)(qr + ch * 16);
      f32x4 x1 = *(const f32x4*)(qr + ch * 16 + 4);
      u32x4 au;
      au[0] = cvt2(x0[0] * QSCALE, x0[1] * QSCALE);
      au[1] = cvt2(x0[2] * QSCALE, x0[3] * QSCALE);
      au[2] = cvt2(x1[0] * QSCALE, x1[1] * QSCALE);
      au[3] = cvt2(x1[2] * QSCALE, x1[3] * QSCALE);
      if (set == 0) aqA[ch] = __builtin_bit_cast(bf16x8, au);
      else          aqB[ch] = __builtin_bit_cast(bf16x8, au);
    }
  }

  f32x16 accA0 = Z16, accA1 = Z16, accB0 = Z16, accB1 = Z16;
  float lsA0 = 0.f, lsA1 = 0.f, lsB0 = 0.f, lsB1 = 0.f;

  const int lo   = max(0, bq0 - WIN);
  const int khiB = min(S_LEN, bq0 + QBLK + WIN);
  const int nt   = (khiB - lo) >> 6;   // {6,8,10}: always even

  // staging assignment (256 threads): K 64x64 via 4 f32x4/thread; V via key-pair x 8 d
  const int krow  = tid >> 2;          // 0..63
  const int kc16  = (tid & 3) << 4;    // 0,16,32,48
  const int key2  = (tid & 31) << 1;   // 0..62 even
  const int key2p = (key2 & ~12) | ((key2 & 4) << 1) | ((key2 & 8) >> 1);  // bits 2<->3
  const int vd8   = (tid >> 5) << 3;   // 0..56

  // hoisted LDS bases
  short* const ksh = (short*)smem;
  short* const vsh = (short*)(smem + 2 * KBYTES);
  const short* const krd = ksh + (kho + c) * KSTR + hi * 8;
  const short* const vrd = vsh + c * VSTR + kho + hi * 8;
  short* const kwr = ksh + krow * KSTR + kc16;
  short* const vwr = vsh + vd8 * VSTR + key2p;

  unsigned koff = (unsigned)(lo + krow) * HEAD_D + kc16;
  unsigned voff = (unsigned)(lo + key2) * HEAD_D + vd8;

  f32x4 k0, k1, k2, k3;          // K staging (16 regs)
  f32x4 v00, v01, v10, v11;      // V staging (16 regs)
  #define LOAD_K() do {                         \
    k0 = *(const f32x4*)(Kp + koff);            \
    k1 = *(const f32x4*)(Kp + koff + 4);        \
    k2 = *(const f32x4*)(Kp + koff + 8);        \
    k3 = *(const f32x4*)(Kp + koff + 12);       \
    koff += KVBLK * HEAD_D;                     \
  } while (0)
  #define LOAD_V() do {                         \
    v00 = *(const f32x4*)(Vp + voff);           \
    v01 = *(const f32x4*)(Vp + voff + 4);       \
    v10 = *(const f32x4*)(Vp + voff + HEAD_D);  \
    v11 = *(const f32x4*)(Vp + voff + HEAD_D + 4); \
    voff += KVBLK * HEAD_D;                     \
  } while (0)
  #define STAGE_TO(BUF) do {                                        \
    u32x4 kw;                                                       \
    kw[0] = cvt2(k0[0], k0[1]);  kw[1] = cvt2(k0[2], k0[3]);        \
    kw[2] = cvt2(k1[0], k1[1]);  kw[3] = cvt2(k1[2], k1[3]);        \
    *(u32x4*)&kwr[(BUF) * KHALF] = kw;                              \
    kw[0] = cvt2(k2[0], k2[1]);  kw[1] = cvt2(k2[2], k2[3]);        \
    kw[2] = cvt2(k3[0], k3[1]);  kw[3] = cvt2(k3[2], k3[3]);        \
    *(u32x4*)&kwr[(BUF) * KHALF + 8] = kw;                          \
    _Pragma("unroll")                                               \
    for (int j = 0; j < 4; ++j)                                     \
      *(unsigned*)&vwr[(BUF) * VHALF + j * VSTR] = cvt2(v00[j], v10[j]); \
    _Pragma("unroll")                                               \
    for (int j = 0; j < 4; ++j)                                     \
      *(unsigned*)&vwr[(BUF) * VHALF + (4 + j) * VSTR] = cvt2(v01[j], v11[j]); \
  } while (0)

  #define TILE_BODY(T, BUF) do {                                                  \
    const int rel_ = lo + ((T) << 6) + kho - q0;                                  \
    /* fully-masked sub-tile for all 64 q x 32 k iff rel_ < -287 or > 319 */      \
    const bool live_ = (rel_ >= -287) && (rel_ <= 319);                           \
    if (live_) {                                                                  \
      f32x16 sA = Z16, sB = Z16;                                                  \
      __builtin_amdgcn_s_setprio(1);                                              \
      _Pragma("unroll")                                                           \
      for (int ch = 0; ch < 4; ++ch) {                                            \
        bf16x8 akf = *(const bf16x8*)&krd[(BUF) * KHALF + ch * 16];               \
        sA = __builtin_amdgcn_mfma_f32_32x32x16_bf16(akf, aqA[ch], sA, 0, 0, 0);  \
        sB = __builtin_amdgcn_mfma_f32_32x32x16_bf16(akf, aqB[ch], sB, 0, 0, 0);  \
      }                                                                           \
      __builtin_amdgcn_s_setprio(0);                                              \
      if ((T) + 1 < nt) LOAD_K();                                                 \
      if (rel_ >= -192 && rel_ <= 224) {   /* band holds for all 64 q x 32 k */   \
        _Pragma("unroll")                                                         \
        for (int g = 0; g < 16; g += 2) {                                         \
          const float a0 = __builtin_amdgcn_exp2f(sA[g]);                         \
          const float a1 = __builtin_amdgcn_exp2f(sA[g + 1]);                     \
          const float b0 = __builtin_amdgcn_exp2f(sB[g]);                         \
          const float b1 = __builtin_amdgcn_exp2f(sB[g + 1]);                     \
          sA[g] = a0; sA[g + 1] = a1; sB[g] = b0; sB[g + 1] = b1;                 \
          lsA0 += a0; lsA1 += a1; lsB0 += b0; lsB1 += b1;                         \
        }                                                                         \
      } else {                                                                    \
        const int bmA = rel_ + 4 * hi - c + WIN;                                  \
        _Pragma("unroll")                                                         \
        for (int g = 0; g < 16; ++g) {                                            \
          const int ro_ = (g & 3) + 8 * (g >> 2);                                 \
          const float a = ((unsigned)(bmA + ro_) <= 2u * WIN)                     \
                            ? __builtin_amdgcn_exp2f(sA[g]) : 0.f;                \
          const float b = ((unsigned)(bmA - 32 + ro_) <= 2u * WIN)                \
                            ? __builtin_amdgcn_exp2f(sB[g]) : 0.f;                \
          sA[g] = a; sB[g] = b;                                                   \
          if (g & 1) { lsA1 += a; lsB1 += b; } else { lsA0 += a; lsB0 += b; }     \
        }                                                                         \
      }                                                                           \
      if ((T) + 1 < nt) LOAD_V();                                                 \
      __builtin_amdgcn_s_setprio(1);                                              \
      _Pragma("unroll")                                                           \
      for (int kt = 0; kt < 2; ++kt) {                                            \
        u32x4 pau;                                                                \
        _Pragma("unroll")                                                         \
        for (int p2 = 0; p2 < 4; ++p2)                                            \
          pau[p2] = cvt2(sA[kt * 8 + 2 * p2], sA[kt * 8 + 2 * p2 + 1]);           \
        const bf16x8 paA = __builtin_bit_cast(bf16x8, pau);                       \
        _Pragma("unroll")                                                         \
        for (int p2 = 0; p2 < 4; ++p2)                                            \
          pau[p2] = cvt2(sB[kt * 8 + 2 * p2], sB[kt * 8 + 2 * p2 + 1]);           \
        const bf16x8 paB = __builtin_bit_cast(bf16x8, pau);                       \
        bf16x8 bv0 = *(const bf16x8*)&vrd[(BUF) * VHALF + kt * 16];               \
        accA0 = __builtin_amdgcn_mfma_f32_32x32x16_bf16(paA, bv0, accA0, 0, 0, 0);\
        accB0 = __builtin_amdgcn_mfma_f32_32x32x16_bf16(paB, bv0, accB0, 0, 0, 0);\
        bf16x8 bv1 = *(const bf16x8*)&vrd[(BUF) * VHALF + kt * 16 + 32 * VSTR];   \
        accA1 = __builtin_amdgcn_mfma_f32_32x32x16_bf16(paA, bv1, accA1, 0, 0, 0);\
        accB1 = __builtin_amdgcn_mfma_f32_32x32x16_bf16(paB, bv1, accB1, 0, 0, 0);\
      }                                                                           \
      __builtin_amdgcn_s_setprio(0);                                              \
    } else {                                                                      \
      if ((T) + 1 < nt) { LOAD_K(); LOAD_V(); }                                   \
    }                                                                             \
    if ((T) + 1 < nt) {                                                           \
      STAGE_TO((BUF) ^ 1);                                                        \
      PUB_BARRIER();                                                              \
    }                                                                             \
  } while (0)

  // prologue: stage tile 0 into buf 0 (one exposed vmcnt wait), then barrier
  LOAD_K();
  LOAD_V();
  STAGE_TO(0);
  PUB_BARRIER();

  for (int t = 0; t < nt; t += 2) {   // nt even: buffer index compile-time
    TILE_BODY(t, 0);
    TILE_BODY(t + 1, 1);
  }

  // ---- epilogue: merge kh halves per (qpair, set); overlay on dead K/V LDS ----
  float lsA = lsA0 + lsA1;  lsA += __shfl_xor(lsA, 32);
  float lsB = lsB0 + lsB1;  lsB += __shfl_xor(lsB, 32);
  __syncthreads();   // all tile reads done -> overlay safe
  float* o_mrg = (float*)smem;                   // [2 qpair][64 q][64 d] = 32 KB
  float* l_par = (float*)(smem + LPAR_OFF);      // [2 kh][2 qpair][2 set][32]
  if (hi == 0) {
    l_par[(((kh * 2 + qpair) * 2 + 0) * 32) + c] = lsA;
    l_par[(((kh * 2 + qpair) * 2 + 1) * 32) + c] = lsB;
  }
  if (kh == 0) {
    float* om = o_mrg + (size_t)qpair * 64 * HEAD_D;
    #pragma unroll
    for (int g = 0; g < 16; ++g) {
      const int qrow = (g & 3) + 8 * (g >> 2) + 4 * hi;
      om[qrow * HEAD_D + c]             = accA0[g];
      om[qrow * HEAD_D + 32 + c]        = accA1[g];
      om[(32 + qrow) * HEAD_D + c]      = accB0[g];
      om[(32 + qrow) * HEAD_D + 32 + c] = accB1[g];
    }
  }
  __syncthreads();
  if (kh == 1) {
    float* lp = l_par + qpair * 2 * 32;          // kh=0 slot, this qpair
    const float* lp1 = lp + 128;                 // kh=1 slot, this qpair
    if (hi == 0) {
      lp[c]      = 1.0f / (lp[c]      + lp1[c]);       // set A inverse
      lp[32 + c] = 1.0f / (lp[32 + c] + lp1[32 + c]);  // set B inverse
    }
    __asm__ volatile("s_waitcnt lgkmcnt(0)" ::: "memory");
    __builtin_amdgcn_sched_barrier(0);
    const float* om = o_mrg + (size_t)qpair * 64 * HEAD_D;
    #pragma unroll
    for (int g = 0; g < 16; ++g) {
      const int qrow = (g & 3) + 8 * (g >> 2) + 4 * hi;
      const float ivA = lp[qrow];        // lane-uniform -> LDS broadcast
      const float ivB = lp[32 + qrow];
      float* orA = Op + (size_t)(q0 + qrow) * HEAD_D;
      float* orB = Op + (size_t)(q0 + 32 + qrow) * HEAD_D;
      orA[c]      = (om[qrow * HEAD_D + c]             + accA0[g]) * ivA;
      orA[32 + c] = (om[qrow * HEAD_D + 32 + c]        + accA1[g]) * ivA;
      orB[c]      = (om[(32 + qrow) * HEAD_D + c]      + accB0[g]) * ivB;
      orB[32 + c] = (om[(32 + qrow) * HEAD_D + 32 + c] + accB1[g]) * ivB;
    }
  }
}

extern "C" void kernel_launch(void* const* d_in, const int* in_sizes, int n_in,
                              void* d_out, int out_size, void* d_ws, size_t ws_size,
                              hipStream_t stream) {
  const float* q = (const float*)d_in[0];
  const float* k = (const float*)d_in[1];
  const float* v = (const float*)d_in[2];
  float* o = (float*)d_out;
  const int blocks = 2 * 16 * (S_LEN / QBLK);  // 1024
  swa_fwd<<<dim3(blocks), dim3(256), 0, stream>>>(q, k, v, o);
}

// Round 14
// 48.170 us; speedup vs baseline: 3.1073x; 1.0988x over previous
//
#include <hip/hip_runtime.h>
#include <hip/hip_bf16.h>

typedef __attribute__((ext_vector_type(4)))  float f32x4;
typedef __attribute__((ext_vector_type(16))) float f32x16;
typedef __attribute__((ext_vector_type(8)))  short bf16x8;
typedef __attribute__((ext_vector_type(4)))  unsigned u32x4;

#define S_LEN 4096
#define HEAD_D 64
#define WIN 256
#define QBLK 256
#define KVBLK 64
#define KSTR 72   // k_lds row stride (shorts)
#define VSTR 72   // vt_lds row stride (shorts), [d][key'] key' = key bits2<->3 swapped
#define QSCALE 0.18033688f   // log2(e)/8 folded into Q; no numerator shift

#define KBYTES (KVBLK * KSTR * 2)    // 9216 B per K buffer
#define VBYTES (HEAD_D * VSTR * 2)   // 9216 B per V buffer
#define KHALF  (KBYTES / 2)          // buffer stride in shorts
#define VHALF  (VBYTES / 2)
#define LPAR_OFF (2 * KBYTES + 2 * VBYTES)          // 36864 (>= 32KB merge overlay)
#define SMEM_BYTES (LPAR_OFF + 2 * 8 * 32 * 4)      // +2KB l partials = 38912

static __device__ __forceinline__ unsigned cvt2(float lo, float hi) {
  unsigned r;
  asm("v_cvt_pk_bf16_f32 %0, %1, %2" : "=v"(r) : "v"(lo), "v"(hi));
  return r;
}

// Publish barrier: drains LDS only; in-flight global prefetch loads ride across.
#define PUB_BARRIER() do {                              \
    __builtin_amdgcn_sched_barrier(0);                  \
    asm volatile("s_waitcnt lgkmcnt(0)" ::: "memory");  \
    __builtin_amdgcn_s_barrier();                       \
    __builtin_amdgcn_sched_barrier(0);                  \
  } while (0)

// 16 waves/block (1024 thr), wave = (qg 0..7, kh 0..1), 32 q per wave (R11 per-wave
// shape -> VGPR ~60). QBLK=256 cuts window-overhead tiles/query 1.67x vs QBLK=128.
// Staging role-split: waves 0-7 stage K, 8-15 stage V.
// launch_bounds (1024,4): cap 128 >= demand ~60 (R7/R12 lesson: never cap below demand).
__global__ __launch_bounds__(1024, 4)
void swa_fwd(const float* __restrict__ Q, const float* __restrict__ K,
             const float* __restrict__ V, float* __restrict__ O) {
  __shared__ __attribute__((aligned(16))) char smem[SMEM_BYTES];

  const int tid  = threadIdx.x;
  const int widx = tid >> 6;
  const int lane = tid & 63;
  const int hi   = lane >> 5;
  const int c    = lane & 31;
  const int kh   = widx & 1;
  const int qg   = widx >> 1;   // 0..7: 32-q group
  const int kho  = kh * 32;

  // XCD swizzle: 512 blocks; 4 contiguous bh per XCD, qb fastest.
  const int pb  = blockIdx.x;
  const int bh  = (pb & 7) * 4 + ((pb >> 3) >> 4);
  const int qb  = (pb >> 3) & 15;
  const int bq0 = qb * QBLK;
  const int q0  = bq0 + qg * 32;   // this wave's 32 q rows

  const size_t base = (size_t)bh * S_LEN * HEAD_D;
  const float* Qp = Q + base;
  const float* Kp = K + base;
  const float* Vp = V + base;
  float*       Op = O + base;

  const f32x16 Z16 = {0.f,0.f,0.f,0.f,0.f,0.f,0.f,0.f,0.f,0.f,0.f,0.f,0.f,0.f,0.f,0.f};

  // ---- Q B-fragments (32 q per wave, R11 shape) ----
  bf16x8 aq[4];
  {
    const float* qr = Qp + (size_t)(q0 + c) * HEAD_D + hi * 8;
    #pragma unroll
    for (int ch = 0; ch < 4; ++ch) {
      f32x4 x0 = *(const f32x4*)(qr + ch * 16);
      f32x4 x1 = *(const f32x4*)(qr + ch * 16 + 4);
      u32x4 au;
      au[0] = cvt2(x0[0] * QSCALE, x0[1] * QSCALE);
      au[1] = cvt2(x0[2] * QSCALE, x0[3] * QSCALE);
      au[2] = cvt2(x1[0] * QSCALE, x1[1] * QSCALE);
      au[3] = cvt2(x1[2] * QSCALE, x1[3] * QSCALE);
      aq[ch] = __builtin_bit_cast(bf16x8, au);
    }
  }

  f32x16 acc0 = Z16, acc1 = Z16;
  float lsA = 0.f, lsB = 0.f;

  const int lo   = max(0, bq0 - WIN);
  const int khiB = min(S_LEN, bq0 + QBLK + WIN);
  const int nt   = (khiB - lo) >> 6;   // 8 or 12: always even

  // ---- staging role split: waves 0-7 K (b128 write), waves 8-15 V (transposed) ----
  const bool isK = (widx < 8);
  const int vtid  = tid & 511;
  const int key2  = (vtid & 31) << 1;
  const int key2p = (key2 & ~12) | ((key2 & 4) << 1) | ((key2 & 8) >> 1);  // bits 2<->3
  const int vd4   = (vtid >> 5) << 2;

  short* const ksh = (short*)smem;
  short* const vsh = (short*)(smem + 2 * KBYTES);
  const short* const krd = ksh + (kho + c) * KSTR + hi * 8;   // QK reads (all waves)
  const short* const vrd = vsh + c * VSTR + kho + hi * 8;     // PV reads (all waves)

  const float* src;      // this thread's staging source
  unsigned off;          // 32-bit element offset, one bump per tile
  int off2;              // second-load offset
  short* swr;            // staging LDS write base
  if (isK) {
    src  = Kp;
    off  = (unsigned)(lo + (vtid >> 3)) * HEAD_D + ((vtid & 7) << 3);
    off2 = 4;
    swr  = ksh + (vtid >> 3) * KSTR + ((vtid & 7) << 3);
  } else {
    src  = Vp;
    off  = (unsigned)(lo + key2) * HEAD_D + vd4;
    off2 = HEAD_D;
    swr  = vsh + vd4 * VSTR + key2p;
  }

  f32x4 r0, r1;   // staging registers (8 VGPR)
  #define LOAD_TILE() do {                       \
    r0 = *(const f32x4*)(src + off);             \
    r1 = *(const f32x4*)(src + off + off2);      \
    off += KVBLK * HEAD_D;                       \
  } while (0)

  #define STAGE_TO(BUF) do {                                          \
    if (isK) {                                                        \
      u32x4 kw;                                                       \
      kw[0] = cvt2(r0[0], r0[1]);  kw[1] = cvt2(r0[2], r0[3]);        \
      kw[2] = cvt2(r1[0], r1[1]);  kw[3] = cvt2(r1[2], r1[3]);        \
      *(u32x4*)&swr[(BUF) * KHALF] = kw;                              \
    } else {                                                          \
      _Pragma("unroll")                                               \
      for (int j = 0; j < 4; ++j)                                     \
        *(unsigned*)&swr[(BUF) * VHALF + j * VSTR] = cvt2(r0[j], r1[j]); \
    }                                                                 \
  } while (0)

  #define TILE_BODY(T, BUF) do {                                                  \
    const int rel_ = lo + ((T) << 6) + kho - q0;                                  \
    const bool live_ = (rel_ >= -287) && (rel_ <= 287);  /* 32q x 32k band hit */ \
    if (live_) {                                                                  \
      f32x16 s = Z16;                                                             \
      __builtin_amdgcn_s_setprio(1);                                              \
      _Pragma("unroll")                                                           \
      for (int ch = 0; ch < 4; ++ch) {                                            \
        bf16x8 akf = *(const bf16x8*)&krd[(BUF) * KHALF + ch * 16];               \
        s = __builtin_amdgcn_mfma_f32_32x32x16_bf16(akf, aq[ch], s, 0, 0, 0);     \
      }                                                                           \
      __builtin_amdgcn_s_setprio(0);                                              \
      if ((T) + 1 < nt) {                                                         \
        STAGE_TO((BUF) ^ 1);                                                      \
        if ((T) + 2 < nt) LOAD_TILE();                                            \
      }                                                                           \
      if (rel_ >= -224 && rel_ <= 224) {   /* whole sub-tile in band */           \
        _Pragma("unroll")                                                         \
        for (int g = 0; g < 16; g += 2) {                                         \
          const float p0 = __builtin_amdgcn_exp2f(s[g]);                          \
          const float p1 = __builtin_amdgcn_exp2f(s[g + 1]);                      \
          s[g] = p0; s[g + 1] = p1; lsA += p0; lsB += p1;                         \
        }                                                                         \
      } else {                                                                    \
        const int bm_ = rel_ + 4 * hi - c + WIN;                                  \
        _Pragma("unroll")                                                         \
        for (int g = 0; g < 16; ++g) {                                            \
          const int ro_ = (g & 3) + 8 * (g >> 2);                                 \
          const float p = ((unsigned)(bm_ + ro_) <= 2u * WIN)                     \
                            ? __builtin_amdgcn_exp2f(s[g]) : 0.f;                 \
          s[g] = p; if (g & 1) lsB += p; else lsA += p;                           \
        }                                                                         \
      }                                                                           \
      __builtin_amdgcn_s_setprio(1);                                              \
      _Pragma("unroll")                                                           \
      for (int kt = 0; kt < 2; ++kt) {                                            \
        u32x4 pau;                                                                \
        _Pragma("unroll")                                                         \
        for (int p2 = 0; p2 < 4; ++p2)                                            \
          pau[p2] = cvt2(s[kt * 8 + 2 * p2], s[kt * 8 + 2 * p2 + 1]);             \
        const bf16x8 pa = __builtin_bit_cast(bf16x8, pau);                        \
        bf16x8 bv0 = *(const bf16x8*)&vrd[(BUF) * VHALF + kt * 16];               \
        acc0 = __builtin_amdgcn_mfma_f32_32x32x16_bf16(pa, bv0, acc0, 0, 0, 0);   \
        bf16x8 bv1 = *(const bf16x8*)&vrd[(BUF) * VHALF + kt * 16 + 32 * VSTR];   \
        acc1 = __builtin_amdgcn_mfma_f32_32x32x16_bf16(pa, bv1, acc1, 0, 0, 0);   \
      }                                                                           \
      __builtin_amdgcn_s_setprio(0);                                              \
    } else {                                                                      \
      if ((T) + 1 < nt) {                                                         \
        STAGE_TO((BUF) ^ 1);                                                      \
        if ((T) + 2 < nt) LOAD_TILE();                                            \
      }                                                                           \
    }                                                                             \
    if ((T) + 1 < nt) PUB_BARRIER();                                              \
  } while (0)

  // prologue: stage tile 0 into buf 0, prefetch tile 1 (rides across barrier)
  LOAD_TILE();
  STAGE_TO(0);
  LOAD_TILE();
  PUB_BARRIER();

  for (int t = 0; t < nt; t += 2) {   // nt even: buffer index compile-time
    TILE_BODY(t, 0);
    TILE_BODY(t + 1, 1);
  }

  // ---- epilogue: merge kh halves, 2 passes over qg halves; overlay on dead K/V LDS ----
  float lsum = lsA + lsB;
  lsum += __shfl_xor(lsum, 32);                  // combine hi halves (same q=c col)
  float* o_mrg = (float*)smem;                   // [4][32][64] f32 = 32 KB per pass
  float* l_par = (float*)(smem + LPAR_OFF);      // [2 kh][8 qg][32]
  __syncthreads();                               // tile reads done -> overlay safe
  if (hi == 0) l_par[(kh * 8 + qg) * 32 + c] = lsum;
  #pragma unroll
  for (int p = 0; p < 2; ++p) {
    if (p) __syncthreads();                      // o_mrg reuse guard
    if (kh == 0 && (qg >> 2) == p) {
      float* om = o_mrg + (qg & 3) * 32 * HEAD_D;
      #pragma unroll
      for (int g = 0; g < 16; ++g) {
        const int qrow = (g & 3) + 8 * (g >> 2) + 4 * hi;
        om[qrow * HEAD_D + c]      = acc0[g];
        om[qrow * HEAD_D + 32 + c] = acc1[g];
      }
    }
    __syncthreads();                             // publish partials (and l_par on p=0)
    if (kh == 1 && (qg >> 2) == p) {
      float* lp = l_par + qg * 32;               // kh=0 slot
      const float* lp1 = l_par + (8 + qg) * 32;  // kh=1 slot
      if (hi == 0) lp[c] = 1.0f / (lp[c] + lp1[c]);
      __asm__ volatile("s_waitcnt lgkmcnt(0)" ::: "memory");   // same-wave w->r
      __builtin_amdgcn_sched_barrier(0);
      const float* om = o_mrg + (qg & 3) * 32 * HEAD_D;
      #pragma unroll
      for (int g = 0; g < 16; ++g) {
        const int qrow = (g & 3) + 8 * (g >> 2) + 4 * hi;
        const float iv = lp[qrow];               // lane-uniform -> LDS broadcast
        float* orow = Op + (size_t)(q0 + qrow) * HEAD_D;
        orow[c]      = (om[qrow * HEAD_D + c]      + acc0[g]) * iv;
        orow[32 + c] = (om[qrow * HEAD_D + 32 + c] + acc1[g]) * iv;
      }
    }
  }
}

extern "C" void kernel_launch(void* const* d_in, const int* in_sizes, int n_in,
                              void* d_out, int out_size, void* d_ws, size_t ws_size,
                              hipStream_t stream) {
  const float* q = (const float*)d_in[0];
  const float* k = (const float*)d_in[1];
  const float* v = (const float*)d_in[2];
  float* o = (float*)d_out;
  const int blocks = 2 * 16 * (S_LEN / QBLK);  // 512
  swa_fwd<<<dim3(blocks), dim3(1024), 0, stream>>>(q, k, v, o);
}